// Round 5
// baseline (192.982 us; speedup 1.0000x reference)
//
#include <hip/hip_runtime.h>
#include <stdint.h>

#define NROWS 2048
#define DDIM  9216
#define GX    1056                    // sum_{bi=0..31}(64-2*bi) : 64x32 tiles right of diagonal

typedef unsigned short u16;
typedef __bf16 bf16x8 __attribute__((ext_vector_type(8)));
typedef float  f32x4  __attribute__((ext_vector_type(4)));

// ws layout: [0] int cnt, [4] float sq, [8] int done, [256..) u16 nf[2048][9216]
#define NF_OFF 256

__device__ __forceinline__ u16 f2bf(float f) {
    uint32_t x = __float_as_uint(f);
    x += 0x7fffu + ((x >> 16) & 1u);          // round-to-nearest-even
    return (u16)(x >> 16);
}

__device__ __forceinline__ void gload16(const u16* g, u16* l) {
    __builtin_amdgcn_global_load_lds(
        (const __attribute__((address_space(1))) uint32_t*)g,
        (__attribute__((address_space(3))) uint32_t*)l, 16, 0, 0);
}

// ---------------- kernel 1: per-row stats + normalize + compact ----------------
__global__ __launch_bounds__(256) void stats_kernel(const float* __restrict__ wgt,
                                                    const float* __restrict__ mask,
                                                    u16* __restrict__ nf,
                                                    int* __restrict__ cnt) {
    int n = blockIdx.x;
    if (mask[n] == 0.0f) return;
    int tid = threadIdx.x;
    const float4* row = (const float4*)(wgt + (size_t)n * DDIM);
    float4 v[9];
    float s = 0.f, ss = 0.f;
#pragma unroll
    for (int i = 0; i < 9; ++i) {
        v[i] = row[tid + 256 * i];
        s  += v[i].x + v[i].y + v[i].z + v[i].w;
        ss += v[i].x * v[i].x + v[i].y * v[i].y + v[i].z * v[i].z + v[i].w * v[i].w;
    }
#pragma unroll
    for (int o = 32; o > 0; o >>= 1) { s += __shfl_down(s, o); ss += __shfl_down(ss, o); }
    __shared__ float rs[4], rss[4];
    __shared__ float smean, sinv;
    __shared__ int   sidx;
    int w = tid >> 6, l = tid & 63;
    if (l == 0) { rs[w] = s; rss[w] = ss; }
    __syncthreads();
    if (tid == 0) {
        float S  = rs[0] + rs[1] + rs[2] + rs[3];
        float SS = rss[0] + rss[1] + rss[2] + rss[3];
        float mean = S / (float)DDIM;
        float var  = SS / (float)DDIM - mean * mean;
        float sd   = sqrtf(fmaxf(var, 0.f));
        if (sd == 0.f) sd = 1.f;
        smean = mean; sinv = 1.f / sd;
        sidx = atomicAdd(cnt, 1);
    }
    __syncthreads();
    float mean = smean, inv = sinv;
    u16* dst = nf + (size_t)sidx * DDIM;
#pragma unroll
    for (int i = 0; i < 9; ++i) {
        int e = (tid + 256 * i) * 4;
        uint32_t lo = (uint32_t)f2bf((v[i].x - mean) * inv) |
                      ((uint32_t)f2bf((v[i].y - mean) * inv) << 16);
        uint32_t hi = (uint32_t)f2bf((v[i].z - mean) * inv) |
                      ((uint32_t)f2bf((v[i].w - mean) * inv) << 16);
        uint2 u; u.x = lo; u.y = hi;
        *(uint2*)(dst + e) = u;
    }
}

// ---------------- kernel 2: 64x32-tile GEMM + square-reduce + finalize ----------------
// 272 active blocks (~1 per CU), 32 KB LDS -> ~5 blocks/CU resident.
// Block-wide staging (m97 2-barrier): per iter BK=128, [A 64 rows; B 32 rows]
// x 256 B = 24 KB via 6 global_load_lds(16B) per wave. K split ACROSS the 4
// waves (wave w owns kk-slot w of each BK step) -> no cross-block combine.
// LDS chunk XOR-swizzled by row via per-lane global-address freedom; read-side
// banks verified 2-way (free). ds_read offsets are loop-invariant immediates.
__global__ __launch_bounds__(256) void gemm_kernel(const u16* __restrict__ nf,
                                                   const int* __restrict__ cnt,
                                                   float* __restrict__ sq,
                                                   int* __restrict__ done,
                                                   float* __restrict__ out) {
    __shared__ u16 ls[16384];                 // 32 KB (staging 24 KB, park 32 KB)
    int A = *cnt;
    int nt32 = (A + 31) >> 5;
    int t = blockIdx.x, bi = 0, len = 64;
    while (t >= len) { t -= len; len -= 2; ++bi; }
    int bj = 2 * bi + t;                      // c0 >= r0 guaranteed
    bool active = (bj < nt32);                // block-uniform
    int tid = threadIdx.x, l = tid & 63, w = tid >> 6;
    int r0 = bi << 6, c0 = bj << 5;

    if (active) {
        int quad = l >> 4, m16 = l & 15;
        // ---- staging addresses: wave w stages rows 24w..24w+23 of [A;B] ----
        const u16* gp[6];
        u16* ld[6];
#pragma unroll
        for (int i = 0; i < 6; ++i) {
            int row = 24 * w + 4 * i + (l >> 4);
            int gr  = (row < 64) ? (r0 + row) : (c0 + row - 64);
            int ch  = (l & 15) ^ (row & 15);  // XOR swizzle, undone at read
            gp[i] = nf + (size_t)gr * DDIM + ch * 8;
            ld[i] = ls + w * 3072 + i * 512;  // wave-uniform base + lane*16
        }
        // ---- loop-invariant read offsets (u16 units) ----
        int cc    = ((w * 4 + quad) ^ m16) * 8;      // swizzled 16B chunk
        int baseA = m16 * 128 + cc;
        int baseB = 8192 + baseA;                    // B rows start at row 64
        f32x4 acc[4][2] = {};

        for (int k0 = 0; k0 < DDIM; k0 += 128) {
            __syncthreads();                  // prev iter's reads done
#pragma unroll
            for (int i = 0; i < 6; ++i) gload16(gp[i] + k0, ld[i]);
            __syncthreads();                  // compiler drains vmcnt before barrier
            bf16x8 af[4], bf[2];
#pragma unroll
            for (int fm = 0; fm < 4; ++fm)
                af[fm] = *(const bf16x8*)&ls[baseA + fm * 2048];
#pragma unroll
            for (int fn = 0; fn < 2; ++fn)
                bf[fn] = *(const bf16x8*)&ls[baseB + fn * 2048];
#pragma unroll
            for (int fm = 0; fm < 4; ++fm)
#pragma unroll
                for (int fn = 0; fn < 2; ++fn)
                    acc[fm][fn] = __builtin_amdgcn_mfma_f32_16x16x32_bf16(
                        af[fm], bf[fn], acc[fm][fn], 0, 0, 0);
        }

        // ---- combine 4 waves' K-partials in LDS, square, mask, reduce ----
        __syncthreads();                      // all K-loop LDS reads complete
        float* fw = (float*)ls + w * 2048;    // 8 KB per wave
#pragma unroll
        for (int fm = 0; fm < 4; ++fm)
#pragma unroll
            for (int fn = 0; fn < 2; ++fn)
                *(f32x4*)&fw[(fm * 2 + fn) * 256 + l * 4] = acc[fm][fn];
        __syncthreads();
        const float* fs = (const float*)ls;
        float local = 0.f;
#pragma unroll
        for (int j = 0; j < 2; ++j) {
            int o = tid * 8 + j * 4;          // element in wave-region layout
            f32x4 v = *(const f32x4*)&fs[o];
            v += *(const f32x4*)&fs[o + 2048];
            v += *(const f32x4*)&fs[o + 4096];
            v += *(const f32x4*)&fs[o + 6144];
            int f = o >> 8, lk = (o >> 2) & 63;
            int rowb = ((f >> 1) << 4) + ((lk >> 4) << 2);  // A-row base (+r)
            int col  = ((f & 1) << 4) + (lk & 15);          // B-col
            int gj = c0 + col;
            if (gj < A) {
#pragma unroll
                for (int r = 0; r < 4; ++r) {
                    int gi = r0 + rowb + r;
                    if (gi < gj) local += v[r] * v[r];
                }
            }
        }
#pragma unroll
        for (int o = 32; o > 0; o >>= 1) local += __shfl_down(local, o);
        if (l == 0) atomicAdd(sq, local);
    }
    __syncthreads();
    if (tid == 0) {
        __threadfence();
        int old = atomicAdd(done, 1);
        if (old == (int)gridDim.x - 1) {      // last block finalizes
            float s = atomicAdd(sq, 0.0f);    // device-coherent read
            long long AA = A;
            long long na = AA * (AA - 1) / 2;
            double loss = 0.0;
            if (na > 0) loss = (double)s / ((double)DDIM * (double)DDIM) / (double)na;
            out[0] = (float)loss;
        }
    }
}

extern "C" void kernel_launch(void* const* d_in, const int* in_sizes, int n_in,
                              void* d_out, int out_size, void* d_ws, size_t ws_size,
                              hipStream_t stream) {
    (void)in_sizes; (void)n_in; (void)out_size; (void)ws_size;
    const float* wgt  = (const float*)d_in[0];
    const float* mask = (const float*)d_in[1];
    float* out = (float*)d_out;
    char*  ws  = (char*)d_ws;

    int*   cnt  = (int*)ws;
    float* sq   = (float*)(ws + 4);
    int*   done = (int*)(ws + 8);
    u16*   nf   = (u16*)(ws + NF_OFF);

    hipMemsetAsync(ws, 0, 256, stream);
    stats_kernel<<<NROWS, 256, 0, stream>>>(wgt, mask, nf, cnt);
    gemm_kernel<<<GX, 256, 0, stream>>>(nf, cnt, sq, done, out);
}

// Round 6
// 190.160 us; speedup vs baseline: 1.0148x; 1.0148x over previous
//
#include <hip/hip_runtime.h>
#include <stdint.h>

#define NROWS 2048
#define DDIM  9216
#define TMAX   16                     // max 128-row tiles per dim
#define TRIMAX 136                    // TMAX*(TMAX+1)/2
#define SLICES 16                     // K-split across blocks (fast path)
#define NF_OFF 256

typedef unsigned short u16;
typedef __bf16 bf16x8 __attribute__((ext_vector_type(8)));
typedef float  f32x4  __attribute__((ext_vector_type(4)));

__device__ __forceinline__ u16 f2bf(float f) {
    uint32_t x = __float_as_uint(f);
    x += 0x7fffu + ((x >> 16) & 1u);          // round-to-nearest-even
    return (u16)(x >> 16);
}

__device__ __forceinline__ void gload16(const u16* g, u16* l) {
    __builtin_amdgcn_global_load_lds(
        (const __attribute__((address_space(1))) uint32_t*)g,
        (__attribute__((address_space(3))) uint32_t*)l, 16, 0, 0);
}

// ---------------- kernel 1: per-row stats + normalize + compact ----------------
__global__ __launch_bounds__(256) void stats_kernel(const float* __restrict__ wgt,
                                                    const float* __restrict__ mask,
                                                    u16* __restrict__ nf,
                                                    int* __restrict__ cnt) {
    int n = blockIdx.x;
    if (mask[n] == 0.0f) return;
    int tid = threadIdx.x;
    const float4* row = (const float4*)(wgt + (size_t)n * DDIM);
    float4 v[9];
    float s = 0.f, ss = 0.f;
#pragma unroll
    for (int i = 0; i < 9; ++i) {
        v[i] = row[tid + 256 * i];
        s  += v[i].x + v[i].y + v[i].z + v[i].w;
        ss += v[i].x * v[i].x + v[i].y * v[i].y + v[i].z * v[i].z + v[i].w * v[i].w;
    }
#pragma unroll
    for (int o = 32; o > 0; o >>= 1) { s += __shfl_down(s, o); ss += __shfl_down(ss, o); }
    __shared__ float rs[4], rss[4];
    __shared__ float smean, sinv;
    __shared__ int   sidx;
    int w = tid >> 6, l = tid & 63;
    if (l == 0) { rs[w] = s; rss[w] = ss; }
    __syncthreads();
    if (tid == 0) {
        float S  = rs[0] + rs[1] + rs[2] + rs[3];
        float SS = rss[0] + rss[1] + rss[2] + rss[3];
        float mean = S / (float)DDIM;
        float var  = SS / (float)DDIM - mean * mean;
        float sd   = sqrtf(fmaxf(var, 0.f));
        if (sd == 0.f) sd = 1.f;
        smean = mean; sinv = 1.f / sd;
        sidx = atomicAdd(cnt, 1);
    }
    __syncthreads();
    float mean = smean, inv = sinv;
    u16* dst = nf + (size_t)sidx * DDIM;
#pragma unroll
    for (int i = 0; i < 9; ++i) {
        int e = (tid + 256 * i) * 4;
        uint32_t lo = (uint32_t)f2bf((v[i].x - mean) * inv) |
                      ((uint32_t)f2bf((v[i].y - mean) * inv) << 16);
        uint32_t hi = (uint32_t)f2bf((v[i].z - mean) * inv) |
                      ((uint32_t)f2bf((v[i].w - mean) * inv) << 16);
        uint2 u; u.x = lo; u.y = hi;
        *(uint2*)(dst + e) = u;
    }
}

// ---------------- kernel 2: 128x128-tile K-sliced GEMM, bf16 partial-C out ----
// m97 shape: 4 waves own 64x64 quadrants, BK=64, block-wide staging of
// 256 rows x 128 B full cache lines per iter (8 gload16/thread), XOR chunk
// swizzle (conflict-free in 8-lane cycle groups). ~576 active blocks
// (36 tiles x 16 K-slices at A~1024) = 2.25 blocks/CU -> cross-block
// latency hiding. Partial C stored bf16 via LDS repack (full-line dwordx4).
__global__ __launch_bounds__(256) void gemm_kernel(const u16* __restrict__ nf,
                                                   const int* __restrict__ cnt,
                                                   char* __restrict__ ws) {
    __shared__ u16 ls[16384];                 // 32 KB staging / C-repack
    int A = *cnt;
    int nt = (A + 127) >> 7;
    int t = blockIdx.x, bi = 0, len = TMAX;   // fixed-16 triangle decode
    while (t >= len) { t -= len; --len; ++bi; }
    int bj = bi + t;
    if (bj >= nt) return;
    int se = (nt <= 9) ? SLICES : 2;          // ws-budget guard (nt>9 ~impossible)
    int s = blockIdx.y;
    if (s >= se) return;
    int ci = bi * nt - (bi * (bi - 1)) / 2 + (bj - bi);   // compact tile rank
    u16* Ct = (u16*)(ws + NF_OFF + (size_t)nt * 128 * DDIM * 2)
              + ((size_t)ci * se + s) * 16384;

    int r0 = bi << 7, c0 = bj << 7;
    int tid = threadIdx.x, l = tid & 63, w = tid >> 6;
    int wr = w >> 1, wc = w & 1;
    int quad = l >> 4, m16 = l & 15;

    // staging: round i (0..3 A, 0..3 B): row = i*32 + w*8 + (l>>3),
    // global 16B-chunk = (l&7) ^ (l>>3)  [XOR swizzle, undone at read]
    int srow = w * 8 + (l >> 3);
    int sch  = ((l & 7) ^ (l >> 3)) * 8;
    const u16* gA = nf + (size_t)(r0 + srow) * DDIM + sch;
    const u16* gB = nf + (size_t)(c0 + srow) * DDIM + sch;
    int kstep = DDIM / se;
    int kbeg = s * kstep, kend = kbeg + kstep;

    f32x4 acc[4][4] = {};
    for (int k0 = kbeg; k0 < kend; k0 += 64) {
        __syncthreads();                      // prev iter's reads done
#pragma unroll
        for (int i = 0; i < 4; ++i)
            gload16(gA + (size_t)(i * 32) * DDIM + k0, ls + i * 2048 + w * 512);
#pragma unroll
        for (int i = 0; i < 4; ++i)
            gload16(gB + (size_t)(i * 32) * DDIM + k0, ls + 8192 + i * 2048 + w * 512);
        __syncthreads();                      // compiler drains vmcnt here
#pragma unroll
        for (int kk = 0; kk < 2; ++kk) {
            int sl8 = ((kk * 4 + quad) ^ (m16 & 7)) * 8;
            bf16x8 af[4], bf[4];
#pragma unroll
            for (int fm = 0; fm < 4; ++fm)
                af[fm] = *(const bf16x8*)&ls[(wr * 64 + fm * 16 + m16) * 64 + sl8];
#pragma unroll
            for (int fn = 0; fn < 4; ++fn)
                bf[fn] = *(const bf16x8*)&ls[8192 + (wc * 64 + fn * 16 + m16) * 64 + sl8];
#pragma unroll
            for (int fm = 0; fm < 4; ++fm)
#pragma unroll
                for (int fn = 0; fn < 4; ++fn)
                    acc[fm][fn] = __builtin_amdgcn_mfma_f32_16x16x32_bf16(
                        af[fm], bf[fn], acc[fm][fn], 0, 0, 0);
        }
    }

    // ---- epilogue: bf16 C tile into LDS, then linear full-line store ----
    __syncthreads();                          // last iter's frag reads done
#pragma unroll
    for (int fm = 0; fm < 4; ++fm)
#pragma unroll
        for (int fn = 0; fn < 4; ++fn) {
            int col = wc * 64 + fn * 16 + m16;
            int rowb = wr * 64 + fm * 16 + quad * 4;
#pragma unroll
            for (int r = 0; r < 4; ++r)
                ls[(rowb + r) * 128 + col] = f2bf(acc[fm][fn][r]);
        }
    __syncthreads();
    const uint4* src = (const uint4*)ls;
    uint4* dst = (uint4*)Ct;
#pragma unroll
    for (int j = 0; j < 8; ++j)
        dst[j * 256 + tid] = src[j * 256 + tid];
}

// ---------------- kernel 3: combine slices, square, mask, reduce, finalize ----
__global__ __launch_bounds__(256) void reduce_kernel(const int* __restrict__ cnt,
                                                     const char* __restrict__ ws,
                                                     float* __restrict__ sq,
                                                     int* __restrict__ done,
                                                     float* __restrict__ out) {
    int A = *cnt;
    int nt = (A + 127) >> 7;
    int t = blockIdx.x, bi = 0, len = TMAX;
    while (t >= len) { t -= len; --len; ++bi; }
    int bj = bi + t;
    int tid = threadIdx.x;
    if (bj < nt) {
        int se = (nt <= 9) ? SLICES : 2;
        int ci = bi * nt - (bi * (bi - 1)) / 2 + (bj - bi);
        const u16* Cb = (const u16*)(ws + NF_OFF + (size_t)nt * 128 * DDIM * 2)
                        + (size_t)ci * se * 16384;
        int r0 = bi << 7, c0 = bj << 7;
        float local = 0.f;
#pragma unroll
        for (int j = 0; j < 8; ++j) {
            int e = (j * 256 + tid) * 8;      // 8-wide chunk base element
            float vs[8] = {0.f, 0.f, 0.f, 0.f, 0.f, 0.f, 0.f, 0.f};
            for (int s = 0; s < se; ++s) {
                bf16x8 v = *(const bf16x8*)&Cb[(size_t)s * 16384 + e];
#pragma unroll
                for (int x = 0; x < 8; ++x) vs[x] += (float)v[x];
            }
            int gi = r0 + (e >> 7);
            int colb = c0 + (e & 127);
#pragma unroll
            for (int x = 0; x < 8; ++x) {
                int gj = colb + x;
                if (gi < gj && gj < A) local += vs[x] * vs[x];
            }
        }
#pragma unroll
        for (int o = 32; o > 0; o >>= 1) local += __shfl_down(local, o);
        __shared__ float ps[4];
        if ((tid & 63) == 0) ps[tid >> 6] = local;
        __syncthreads();
        if (tid == 0) atomicAdd(sq, ps[0] + ps[1] + ps[2] + ps[3]);
    }
    __syncthreads();
    if (tid == 0) {
        __threadfence();
        int old = atomicAdd(done, 1);
        if (old == (int)gridDim.x - 1) {      // last block finalizes
            float sv = atomicAdd(sq, 0.0f);   // device-coherent read
            long long AA = A;
            long long na = AA * (AA - 1) / 2;
            double loss = 0.0;
            if (na > 0) loss = (double)sv / ((double)DDIM * (double)DDIM) / (double)na;
            out[0] = (float)loss;
        }
    }
}

extern "C" void kernel_launch(void* const* d_in, const int* in_sizes, int n_in,
                              void* d_out, int out_size, void* d_ws, size_t ws_size,
                              hipStream_t stream) {
    (void)in_sizes; (void)n_in; (void)out_size; (void)ws_size;
    const float* wgt  = (const float*)d_in[0];
    const float* mask = (const float*)d_in[1];
    float* out = (float*)d_out;
    char*  ws  = (char*)d_ws;

    int*   cnt  = (int*)ws;
    float* sq   = (float*)(ws + 4);
    int*   done = (int*)(ws + 8);
    u16*   nf   = (u16*)(ws + NF_OFF);

    hipMemsetAsync(ws, 0, 256, stream);
    stats_kernel<<<NROWS, 256, 0, stream>>>(wgt, mask, nf, cnt);
    gemm_kernel<<<dim3(TRIMAX, SLICES), 256, 0, stream>>>(nf, cnt, ws);
    reduce_kernel<<<TRIMAX, 256, 0, stream>>>(cnt, ws, sq, done, out);
}

// Round 7
// 180.264 us; speedup vs baseline: 1.0706x; 1.0549x over previous
//
#include <hip/hip_runtime.h>
#include <stdint.h>

#define NROWS 2048
#define DDIM  9216
#define TMAX   16                     // max 128-row tiles per dim
#define TRIMAX 136                    // TMAX*(TMAX+1)/2
#define SLICES 18                     // K-split across blocks (fast path, 512/slice)
#define NF_OFF 256
#define CP_OFF (NF_OFF + 2048 * DDIM) // fp8 nf is 18.87 MB; partials after it

typedef unsigned short u16;
typedef uint8_t u8;
typedef long f8x8;                    // 8 fp8 = 2 VGPRs (i64) MFMA operand
typedef __bf16 bf16x8 __attribute__((ext_vector_type(8)));
typedef float  f32x4  __attribute__((ext_vector_type(4)));

__device__ __forceinline__ u16 f2bf(float f) {
    uint32_t x = __float_as_uint(f);
    x += 0x7fffu + ((x >> 16) & 1u);          // round-to-nearest-even
    return (u16)(x >> 16);
}

__device__ __forceinline__ void gload16(const u8* g, u8* l) {
    __builtin_amdgcn_global_load_lds(
        (const __attribute__((address_space(1))) uint32_t*)g,
        (__attribute__((address_space(3))) uint32_t*)l, 16, 0, 0);
}

// ---------------- kernel 1: per-row stats + normalize + compact (fp8 out) ------
__global__ __launch_bounds__(256) void stats_kernel(const float* __restrict__ wgt,
                                                    const float* __restrict__ mask,
                                                    u8* __restrict__ nf,
                                                    int* __restrict__ cnt) {
    int n = blockIdx.x;
    if (mask[n] == 0.0f) return;
    int tid = threadIdx.x;
    const float4* row = (const float4*)(wgt + (size_t)n * DDIM);
    float4 v[9];
    float s = 0.f, ss = 0.f;
#pragma unroll
    for (int i = 0; i < 9; ++i) {
        v[i] = row[tid + 256 * i];
        s  += v[i].x + v[i].y + v[i].z + v[i].w;
        ss += v[i].x * v[i].x + v[i].y * v[i].y + v[i].z * v[i].z + v[i].w * v[i].w;
    }
#pragma unroll
    for (int o = 32; o > 0; o >>= 1) { s += __shfl_down(s, o); ss += __shfl_down(ss, o); }
    __shared__ float rs[4], rss[4];
    __shared__ float smean, sinv;
    __shared__ int   sidx;
    int w = tid >> 6, l = tid & 63;
    if (l == 0) { rs[w] = s; rss[w] = ss; }
    __syncthreads();
    if (tid == 0) {
        float S  = rs[0] + rs[1] + rs[2] + rs[3];
        float SS = rss[0] + rss[1] + rss[2] + rss[3];
        float mean = S / (float)DDIM;
        float var  = SS / (float)DDIM - mean * mean;
        float sd   = sqrtf(fmaxf(var, 0.f));
        if (sd == 0.f) sd = 1.f;              // reference: std==0 -> 1
        smean = mean; sinv = 1.f / sd;
        sidx = atomicAdd(cnt, 1);             // compacted slot (order irrelevant)
    }
    __syncthreads();
    float mean = smean, inv = sinv;
    uint32_t* dst = (uint32_t*)(nf + (size_t)sidx * DDIM);
#pragma unroll
    for (int i = 0; i < 9; ++i) {
        int e = tid + 256 * i;                // dword index == float4 index
        int p = __builtin_amdgcn_cvt_pk_fp8_f32((v[i].x - mean) * inv,
                                                (v[i].y - mean) * inv, 0, false);
        p = __builtin_amdgcn_cvt_pk_fp8_f32((v[i].z - mean) * inv,
                                            (v[i].w - mean) * inv, p, true);
        dst[e] = (uint32_t)p;
    }
}

// ---------------- kernel 2: 128x128-tile K-sliced fp8 GEMM, bf16 partial-C ----
// 4 waves own 64x64 quadrants; BK=128 fp8 = one full 128 B cache line per row
// per iter (stage A 16 KB + B 16 KB = 8 gload16/thread). 36 tiles x 18 slices
// ~= 648 active blocks (~2.5/CU) for cross-block latency hiding. 16B-chunk XOR
// swizzle via per-lane global address; ds_read_b64 lands uniform 4 lanes per
// bank-pair (width floor, no excess conflict).
__global__ __launch_bounds__(256) void gemm_kernel(const u8* __restrict__ nf,
                                                   const int* __restrict__ cnt,
                                                   char* __restrict__ ws) {
    __shared__ u8 ls[32768];                  // staging A|B; reused for C repack
    int A = *cnt;
    int nt = (A + 127) >> 7;
    int t = blockIdx.x, bi = 0, len = TMAX;   // fixed-16 triangle decode
    while (t >= len) { t -= len; --len; ++bi; }
    int bj = bi + t;
    if (bj >= nt) return;
    int se = (nt <= 9) ? SLICES : 2;          // ws-budget guard (nt>9 ~impossible)
    int s = blockIdx.y;
    if (s >= se) return;
    int ci = bi * nt - (bi * (bi - 1)) / 2 + (bj - bi);
    u16* Ct = (u16*)(ws + CP_OFF) + ((size_t)ci * se + s) * 16384;

    int r0 = bi << 7, c0 = bj << 7;
    int tid = threadIdx.x, l = tid & 63, w = tid >> 6;
    int wr = w >> 1, wc = w & 1;
    int quad = l >> 4, m16 = l & 15;

    // staging: round i: row = i*32 + w*8 + (l>>3); global chunk = (l&7)^(l>>3)
    int srow = w * 8 + (l >> 3);
    int sch  = ((l & 7) ^ (l >> 3)) * 16;     // fp8 elements == bytes
    const u8* gA = nf + (size_t)(r0 + srow) * DDIM + sch;
    const u8* gB = nf + (size_t)(c0 + srow) * DDIM + sch;
    int kstep = DDIM / se;                    // 512 (se=18) or 4608 (se=2)
    int kbeg = s * kstep, kend = kbeg + kstep;

    f32x4 acc[4][4] = {};
    for (int k0 = kbeg; k0 < kend; k0 += 128) {
        __syncthreads();                      // prev iter's LDS reads done
#pragma unroll
        for (int i = 0; i < 4; ++i)
            gload16(gA + (size_t)(i * 32) * DDIM + k0, ls + i * 4096 + w * 1024);
#pragma unroll
        for (int i = 0; i < 4; ++i)
            gload16(gB + (size_t)(i * 32) * DDIM + k0, ls + 16384 + i * 4096 + w * 1024);
        __syncthreads();                      // compiler drains vmcnt here
#pragma unroll
        for (int kk = 0; kk < 4; ++kk) {
            int g   = kk * 4 + quad;          // 8-byte granule 0..15
            int off = (((g >> 1) ^ (m16 & 7)) << 4) + ((g & 1) << 3);
            f8x8 af[4], bf[4];
#pragma unroll
            for (int fm = 0; fm < 4; ++fm)
                af[fm] = *(const f8x8*)&ls[(wr * 64 + fm * 16 + m16) * 128 + off];
#pragma unroll
            for (int fn = 0; fn < 4; ++fn)
                bf[fn] = *(const f8x8*)&ls[16384 + (wc * 64 + fn * 16 + m16) * 128 + off];
#pragma unroll
            for (int fm = 0; fm < 4; ++fm)
#pragma unroll
                for (int fn = 0; fn < 4; ++fn)
                    acc[fm][fn] = __builtin_amdgcn_mfma_f32_16x16x32_fp8_fp8(
                        af[fm], bf[fn], acc[fm][fn], 0, 0, 0);
        }
    }

    // ---- epilogue: bf16 C tile into LDS (32 KB), linear full-line store ----
    __syncthreads();                          // last iter's frag reads done
    u16* lsc = (u16*)ls;
#pragma unroll
    for (int fm = 0; fm < 4; ++fm)
#pragma unroll
        for (int fn = 0; fn < 4; ++fn) {
            int col  = wc * 64 + fn * 16 + m16;
            int rowb = wr * 64 + fm * 16 + quad * 4;
#pragma unroll
            for (int r = 0; r < 4; ++r)
                lsc[(rowb + r) * 128 + col] = f2bf(acc[fm][fn][r]);
        }
    __syncthreads();
    const uint4* src = (const uint4*)ls;
    uint4* dst = (uint4*)Ct;
#pragma unroll
    for (int j = 0; j < 8; ++j)
        dst[j * 256 + tid] = src[j * 256 + tid];
}

// ---------------- kernel 3: combine slices, square, mask, reduce, finalize ----
__global__ __launch_bounds__(256) void reduce_kernel(const int* __restrict__ cnt,
                                                     const char* __restrict__ ws,
                                                     float* __restrict__ sq,
                                                     int* __restrict__ done,
                                                     float* __restrict__ out) {
    int A = *cnt;
    int nt = (A + 127) >> 7;
    int t = blockIdx.x, bi = 0, len = TMAX;
    while (t >= len) { t -= len; --len; ++bi; }
    int bj = bi + t;
    int tid = threadIdx.x;
    if (bj < nt) {
        int se = (nt <= 9) ? SLICES : 2;
        int ci = bi * nt - (bi * (bi - 1)) / 2 + (bj - bi);
        const u16* Cb = (const u16*)(ws + CP_OFF) + (size_t)ci * se * 16384;
        int r0 = bi << 7, c0 = bj << 7;
        float local = 0.f;
#pragma unroll
        for (int j = 0; j < 8; ++j) {
            int e = (j * 256 + tid) * 8;      // 8-wide chunk base element
            float vs[8] = {0.f, 0.f, 0.f, 0.f, 0.f, 0.f, 0.f, 0.f};
            for (int s = 0; s < se; ++s) {
                bf16x8 v = *(const bf16x8*)&Cb[(size_t)s * 16384 + e];
#pragma unroll
                for (int x = 0; x < 8; ++x) vs[x] += (float)v[x];
            }
            int gi = r0 + (e >> 7);
            int colb = c0 + (e & 127);
#pragma unroll
            for (int x = 0; x < 8; ++x) {
                int gj = colb + x;
                if (gi < gj && gj < A) local += vs[x] * vs[x];
            }
        }
#pragma unroll
        for (int o = 32; o > 0; o >>= 1) local += __shfl_down(local, o);
        __shared__ float ps[4];
        if ((tid & 63) == 0) ps[tid >> 6] = local;
        __syncthreads();
        if (tid == 0) atomicAdd(sq, ps[0] + ps[1] + ps[2] + ps[3]);
    }
    __syncthreads();
    if (tid == 0) {
        __threadfence();
        int old = atomicAdd(done, 1);
        if (old == (int)gridDim.x - 1) {      // last block finalizes
            float sv = atomicAdd(sq, 0.0f);   // device-coherent read
            long long AA = A;
            long long na = AA * (AA - 1) / 2;
            double loss = 0.0;
            if (na > 0) loss = (double)sv / ((double)DDIM * (double)DDIM) / (double)na;
            out[0] = (float)loss;
        }
    }
}

extern "C" void kernel_launch(void* const* d_in, const int* in_sizes, int n_in,
                              void* d_out, int out_size, void* d_ws, size_t ws_size,
                              hipStream_t stream) {
    (void)in_sizes; (void)n_in; (void)out_size; (void)ws_size;
    const float* wgt  = (const float*)d_in[0];
    const float* mask = (const float*)d_in[1];
    float* out = (float*)d_out;
    char*  ws  = (char*)d_ws;

    int*   cnt  = (int*)ws;
    float* sq   = (float*)(ws + 4);
    int*   done = (int*)(ws + 8);
    u8*    nf   = (u8*)(ws + NF_OFF);

    hipMemsetAsync(ws, 0, 256, stream);
    stats_kernel<<<NROWS, 256, 0, stream>>>(wgt, mask, nf, cnt);
    gemm_kernel<<<dim3(TRIMAX, SLICES), 256, 0, stream>>>(nf, cnt, ws);
    reduce_kernel<<<TRIMAX, 256, 0, stream>>>(cnt, ws, sq, done, out);
}